// Round 2
// baseline (42715.582 us; speedup 1.0000x reference)
//
#include <hip/hip_runtime.h>

// NaiveRNN on MI355X: persistent kernel, 8 independent groups (one per XCD
// under blockIdx%8 round-robin), 32 wgs/group. Each wg: 32 output columns,
// W_hh/W_ih slices pre-packed as MFMA B-fragments in LDS. h broadcast through
// agent-scope atomics (correct regardless of XCD placement). x_proj for t+1 is
// computed in the sync bubble after signaling step t.

typedef __attribute__((ext_vector_type(8))) short bf16x8;   // 8 bf16 = 4 VGPRs
typedef __attribute__((ext_vector_type(4))) float f32x4;

#define TT 2048
#define II 512
#define HH 1024

// LDS layout (dynamic, 98816 B):
// [0,      65536): W_hh B-frags: slot ((kk*2+n2)*64 + lane)*16 B, kk<32
// [65536,  98304): W_ih B-frags: slot ((kk*2+n2)*64 + lane)*16 B, kk<16
// [98304,  98816): hT transpose buffer, 8 rows x 32 cols bf16
#define LDS_WHH 0
#define LDS_WIH 65536
#define LDS_HT  98304
#define LDS_TOTAL 98816

__device__ __forceinline__ unsigned short f2bf(float f) {
  union { __bf16 b; unsigned short s; } u;
  u.b = (__bf16)f;                       // RNE convert
  return u.s;
}

// x_proj fragments for time step tx: x[n2] = sum_k inputs[b][tx][k]*W_ih[j][k]
__device__ __forceinline__ void compute_xp(const float* __restrict__ inp,
                                           char* smem, int b0, int tx, int lane,
                                           f32x4& x0, f32x4& x1) {
  const int c = lane & 15, lg = lane >> 4;
  f32x4 z = {0.f, 0.f, 0.f, 0.f};
  x0 = z; x1 = z;
  const bool act = c < 8;                // batch rows 0..7 of the 16-row M tile
  const float* base = inp + ((size_t)(b0 + (act ? c : 0)) * TT + tx) * II + lg * 8;
  #pragma unroll 4
  for (int kk = 0; kk < 16; ++kk) {
    bf16x8 af = {0, 0, 0, 0, 0, 0, 0, 0};
    if (act) {
      f32x4 a = *(const f32x4*)(base + kk * 32);
      f32x4 b = *(const f32x4*)(base + kk * 32 + 4);
      #pragma unroll
      for (int i = 0; i < 4; ++i) {
        af[i]     = (short)f2bf(a[i]);
        af[4 + i] = (short)f2bf(b[i]);
      }
    }
    const bf16x8* w0 = (const bf16x8*)(smem + LDS_WIH + (size_t)((kk * 2 + 0) * 64 + lane) * 16);
    const bf16x8* w1 = (const bf16x8*)(smem + LDS_WIH + (size_t)((kk * 2 + 1) * 64 + lane) * 16);
    x0 = __builtin_amdgcn_mfma_f32_16x16x32_bf16(af, *w0, x0, 0, 0, 0);
    x1 = __builtin_amdgcn_mfma_f32_16x16x32_bf16(af, *w1, x1, 0, 0, 0);
  }
}

extern "C" __global__ void __launch_bounds__(64)
rnn_kernel(const float* __restrict__ inp,   // [64][2048][512]
           const float* __restrict__ Wih,   // [1024][512]
           const float* __restrict__ bih,   // [1024]
           const float* __restrict__ Whh,   // [1024][1024]
           const float* __restrict__ bhh,   // [1024]
           float* __restrict__ out,         // [64][2048][1024]
           unsigned long long* __restrict__ hbuf,  // [2][64][256] u64 (bf16 x4)
           unsigned int* __restrict__ ctr)  // [8] padded to 64 uints apart
{
  extern __shared__ char smem[];
  const int lane = threadIdx.x;            // 0..63
  const int c  = lane & 15;
  const int lg = lane >> 4;
  const int wg = blockIdx.x;               // 0..255
  const int g  = wg & 7;                   // group (XCD under %8 round-robin)
  const int w  = wg >> 3;                  // 0..31 within group
  const int jb = w * 32;                   // output-column base
  const int b0 = g * 8;                    // batch base

  // ---- stage W_hh fragments: lane holds Whh[jb+n2*16+c][kk*32+lg*8 + 0..7] ----
  for (int kk = 0; kk < 32; ++kk)
    for (int n2 = 0; n2 < 2; ++n2) {
      const float* s = Whh + (size_t)(jb + n2 * 16 + c) * HH + kk * 32 + lg * 8;
      f32x4 a = *(const f32x4*)s;
      f32x4 b = *(const f32x4*)(s + 4);
      bf16x8 f;
      #pragma unroll
      for (int i = 0; i < 4; ++i) { f[i] = (short)f2bf(a[i]); f[4 + i] = (short)f2bf(b[i]); }
      *(bf16x8*)(smem + LDS_WHH + (size_t)((kk * 2 + n2) * 64 + lane) * 16) = f;
    }
  // ---- stage W_ih fragments ----
  for (int kk = 0; kk < 16; ++kk)
    for (int n2 = 0; n2 < 2; ++n2) {
      const float* s = Wih + (size_t)(jb + n2 * 16 + c) * II + kk * 32 + lg * 8;
      f32x4 a = *(const f32x4*)s;
      f32x4 b = *(const f32x4*)(s + 4);
      bf16x8 f;
      #pragma unroll
      for (int i = 0; i < 4; ++i) { f[i] = (short)f2bf(a[i]); f[4 + i] = (short)f2bf(b[i]); }
      *(bf16x8*)(smem + LDS_WIH + (size_t)((kk * 2 + n2) * 64 + lane) * 16) = f;
    }
  const float bs0 = bih[jb + c]      + bhh[jb + c];
  const float bs1 = bih[jb + 16 + c] + bhh[jb + 16 + c];
  __syncthreads();

  const bool act = c < 8;
  f32x4 x0, x1;
  compute_xp(inp, smem, b0, 0, lane, x0, x1);

  for (int t = 0; t < TT; ++t) {
    f32x4 acc0 = x0, acc1 = x1;          // start from x_proj[t] (+h part below)

    if (t > 0) {
      if (lane == 0) {
        const unsigned tgt = 32u * (unsigned)t;
        while (__hip_atomic_load(ctr + g * 64, __ATOMIC_RELAXED, __HIP_MEMORY_SCOPE_AGENT) < tgt)
          __builtin_amdgcn_s_sleep(1);
      }
      __builtin_amdgcn_fence(__ATOMIC_ACQUIRE, "agent");
      const unsigned long long* hrow =
          hbuf + ((size_t)(t & 1) * 64 + b0 + (act ? c : 0)) * 256;
      #pragma unroll 8
      for (int kk = 0; kk < 32; ++kk) {
        bf16x8 af = {0, 0, 0, 0, 0, 0, 0, 0};
        if (act) {
          unsigned long long q0 = __hip_atomic_load(hrow + kk * 8 + lg * 2,
                                                    __ATOMIC_RELAXED, __HIP_MEMORY_SCOPE_AGENT);
          unsigned long long q1 = __hip_atomic_load(hrow + kk * 8 + lg * 2 + 1,
                                                    __ATOMIC_RELAXED, __HIP_MEMORY_SCOPE_AGENT);
          union { unsigned long long q[2]; bf16x8 v; } u;
          u.q[0] = q0; u.q[1] = q1; af = u.v;
        }
        const bf16x8* w0 = (const bf16x8*)(smem + LDS_WHH + (size_t)((kk * 2 + 0) * 64 + lane) * 16);
        const bf16x8* w1 = (const bf16x8*)(smem + LDS_WHH + (size_t)((kk * 2 + 1) * 64 + lane) * 16);
        acc0 = __builtin_amdgcn_mfma_f32_16x16x32_bf16(af, *w0, acc0, 0, 0, 0);
        acc1 = __builtin_amdgcn_mfma_f32_16x16x32_bf16(af, *w1, acc1, 0, 0, 0);
      }
    }

    // ---- epilogue: bias + relu, store fp32 out, bf16 into LDS transpose tile ----
    if (lg < 2) {
      #pragma unroll
      for (int i = 0; i < 4; ++i) {
        const int r4 = lg * 4 + i;       // batch row 0..7
        const size_t ob = ((size_t)(b0 + r4) * TT + t) * HH + jb + c;
        const float p0 = fmaxf(acc0[i] + bs0, 0.f);
        const float p1 = fmaxf(acc1[i] + bs1, 0.f);
        out[ob]      = p0;
        out[ob + 16] = p1;
        *(unsigned short*)(smem + LDS_HT + r4 * 64 + c * 2)        = f2bf(p0);
        *(unsigned short*)(smem + LDS_HT + r4 * 64 + (16 + c) * 2) = f2bf(p1);
      }
    }
    __syncthreads();                     // order hT writes before reads (1 wave)

    // ---- flush hT: lane -> (row = lane>>3, 4 cols at (lane&7)*4), one u64 ----
    {
      unsigned long long q =
          *(const unsigned long long*)(smem + LDS_HT + (lane >> 3) * 64 + (lane & 7) * 8);
      unsigned long long* dst = hbuf + ((size_t)((t + 1) & 1) * 64 + b0 + (lane >> 3)) * 256
                                + (size_t)(jb / 4 + (lane & 7));
      __hip_atomic_store(dst, q, __ATOMIC_RELAXED, __HIP_MEMORY_SCOPE_AGENT);
    }
    __builtin_amdgcn_fence(__ATOMIC_RELEASE, "agent");
    if (lane == 0)
      __hip_atomic_fetch_add(ctr + g * 64, 1u, __ATOMIC_RELAXED, __HIP_MEMORY_SCOPE_AGENT);

    // ---- fill the sync bubble with x_proj for t+1 (no cross-wg dependency) ----
    if (t + 1 < TT) compute_xp(inp, smem, b0, t + 1, lane, x0, x1);
  }
}

extern "C" void kernel_launch(void* const* d_in, const int* in_sizes, int n_in,
                              void* d_out, int out_size, void* d_ws, size_t ws_size,
                              hipStream_t stream) {
  const float* inp = (const float*)d_in[0];
  const float* Wih = (const float*)d_in[1];
  const float* bih = (const float*)d_in[2];
  const float* Whh = (const float*)d_in[3];
  const float* bhh = (const float*)d_in[4];
  float* out = (float*)d_out;

  // ws: [0, 262144) hbuf (2 x 64 x 1024 bf16); [262144, +2048) counters (8 x 64 uints)
  unsigned long long* hbuf = (unsigned long long*)d_ws;
  unsigned int* ctr = (unsigned int*)((char*)d_ws + 262144);

  hipMemsetAsync(ctr, 0, 2048, stream);
  hipFuncSetAttribute((const void*)rnn_kernel,
                      hipFuncAttributeMaxDynamicSharedMemorySize, LDS_TOTAL);
  hipLaunchKernelGGL(rnn_kernel, dim3(256), dim3(64), LDS_TOTAL, stream,
                     inp, Wih, bih, Whh, bhh, out, hbuf, ctr);
}

// Round 5
// 36089.224 us; speedup vs baseline: 1.1836x; 1.1836x over previous
//
#include <hip/hip_runtime.h>

// NaiveRNN on MI355X: persistent kernel, 8 independent groups (one per XCD
// under blockIdx%8 round-robin), 32 wgs/group. Each wg: 32 output columns,
// W_hh/W_ih slices pre-packed as MFMA B-fragments in LDS. h broadcast through
// agent-scope ATOMICS only (sc1-flagged, individually coherent at L3) —
// NO agent-scope fences (fence acquire/release agent emit buffer_inv /
// buffer_wbl2 = full-L2 walks; 32 wgs x 2048 steps of those was ~20us/step).
// Release ordering = s_waitcnt vmcnt(0) between h-stores and ctr increment.
// Acquire ordering = poll branch dependency + compiler barrier.

typedef __attribute__((ext_vector_type(8))) short bf16x8;   // 8 bf16 = 4 VGPRs
typedef __attribute__((ext_vector_type(4))) float f32x4;

#define TT 2048
#define II 512
#define HH 1024

// LDS layout (dynamic, 98816 B):
// [0,      65536): W_hh B-frags: slot ((kk*2+n2)*64 + lane)*16 B, kk<32
// [65536,  98304): W_ih B-frags: slot ((kk*2+n2)*64 + lane)*16 B, kk<16
// [98304,  98816): hT transpose buffer, 8 rows x 32 cols bf16
#define LDS_WHH 0
#define LDS_WIH 65536
#define LDS_HT  98304
#define LDS_TOTAL 98816

__device__ __forceinline__ unsigned short f2bf(float f) {
  union { __bf16 b; unsigned short s; } u;
  u.b = (__bf16)f;                       // RNE convert
  return u.s;
}

// x_proj fragments for time step tx: x[n2] = sum_k inputs[b][tx][k]*W_ih[j][k]
__device__ __forceinline__ void compute_xp(const float* __restrict__ inp,
                                           char* smem, int b0, int tx, int lane,
                                           f32x4& x0, f32x4& x1) {
  const int c = lane & 15, lg = lane >> 4;
  f32x4 z = {0.f, 0.f, 0.f, 0.f};
  x0 = z; x1 = z;
  const bool act = c < 8;                // batch rows 0..7 of the 16-row M tile
  const float* base = inp + ((size_t)(b0 + (act ? c : 0)) * TT + tx) * II + lg * 8;
  #pragma unroll 4
  for (int kk = 0; kk < 16; ++kk) {
    bf16x8 af = {0, 0, 0, 0, 0, 0, 0, 0};
    if (act) {
      f32x4 a = *(const f32x4*)(base + kk * 32);
      f32x4 b = *(const f32x4*)(base + kk * 32 + 4);
      #pragma unroll
      for (int i = 0; i < 4; ++i) {
        af[i]     = (short)f2bf(a[i]);
        af[4 + i] = (short)f2bf(b[i]);
      }
    }
    const bf16x8* w0 = (const bf16x8*)(smem + LDS_WIH + (size_t)((kk * 2 + 0) * 64 + lane) * 16);
    const bf16x8* w1 = (const bf16x8*)(smem + LDS_WIH + (size_t)((kk * 2 + 1) * 64 + lane) * 16);
    x0 = __builtin_amdgcn_mfma_f32_16x16x32_bf16(af, *w0, x0, 0, 0, 0);
    x1 = __builtin_amdgcn_mfma_f32_16x16x32_bf16(af, *w1, x1, 0, 0, 0);
  }
}

extern "C" __global__ void __launch_bounds__(64)
rnn_kernel(const float* __restrict__ inp,   // [64][2048][512]
           const float* __restrict__ Wih,   // [1024][512]
           const float* __restrict__ bih,   // [1024]
           const float* __restrict__ Whh,   // [1024][1024]
           const float* __restrict__ bhh,   // [1024]
           float* __restrict__ out,         // [64][2048][1024]
           unsigned long long* __restrict__ hbuf,  // [2][64][256] u64 (bf16 x4)
           unsigned int* __restrict__ ctr)  // [8] padded to 64 uints apart
{
  extern __shared__ char smem[];
  const int lane = threadIdx.x;            // 0..63
  const int c  = lane & 15;
  const int lg = lane >> 4;
  const int wg = blockIdx.x;               // 0..255
  const int g  = wg & 7;                   // group (XCD under %8 round-robin)
  const int w  = wg >> 3;                  // 0..31 within group
  const int jb = w * 32;                   // output-column base
  const int b0 = g * 8;                    // batch base

  // ---- stage W_hh fragments: lane holds Whh[jb+n2*16+c][kk*32+lg*8 + 0..7] ----
  for (int kk = 0; kk < 32; ++kk)
    for (int n2 = 0; n2 < 2; ++n2) {
      const float* s = Whh + (size_t)(jb + n2 * 16 + c) * HH + kk * 32 + lg * 8;
      f32x4 a = *(const f32x4*)s;
      f32x4 b = *(const f32x4*)(s + 4);
      bf16x8 f;
      #pragma unroll
      for (int i = 0; i < 4; ++i) { f[i] = (short)f2bf(a[i]); f[4 + i] = (short)f2bf(b[i]); }
      *(bf16x8*)(smem + LDS_WHH + (size_t)((kk * 2 + n2) * 64 + lane) * 16) = f;
    }
  // ---- stage W_ih fragments ----
  for (int kk = 0; kk < 16; ++kk)
    for (int n2 = 0; n2 < 2; ++n2) {
      const float* s = Wih + (size_t)(jb + n2 * 16 + c) * II + kk * 32 + lg * 8;
      f32x4 a = *(const f32x4*)s;
      f32x4 b = *(const f32x4*)(s + 4);
      bf16x8 f;
      #pragma unroll
      for (int i = 0; i < 4; ++i) { f[i] = (short)f2bf(a[i]); f[4 + i] = (short)f2bf(b[i]); }
      *(bf16x8*)(smem + LDS_WIH + (size_t)((kk * 2 + n2) * 64 + lane) * 16) = f;
    }
  const float bs0 = bih[jb + c]      + bhh[jb + c];
  const float bs1 = bih[jb + 16 + c] + bhh[jb + 16 + c];
  __syncthreads();

  const bool act = c < 8;
  f32x4 x0, x1;
  compute_xp(inp, smem, b0, 0, lane, x0, x1);

  for (int t = 0; t < TT; ++t) {
    f32x4 acc0 = x0, acc1 = x1;          // start from x_proj[t] (+h part below)

    if (t > 0) {
      if (lane == 0) {
        const unsigned tgt = 32u * (unsigned)t;
        while (__hip_atomic_load(ctr + g * 64, __ATOMIC_RELAXED, __HIP_MEMORY_SCOPE_AGENT) < tgt)
          __builtin_amdgcn_s_sleep(1);
      }
      // acquire: HW order is free (loads below can't issue before the poll
      // branch resolves); just stop the compiler from hoisting.
      asm volatile("" ::: "memory");
      const unsigned long long* hrow =
          hbuf + ((size_t)(t & 1) * 64 + b0 + (act ? c : 0)) * 256;
      #pragma unroll 8
      for (int kk = 0; kk < 32; ++kk) {
        bf16x8 af = {0, 0, 0, 0, 0, 0, 0, 0};
        if (act) {
          unsigned long long q0 = __hip_atomic_load(hrow + kk * 8 + lg * 2,
                                                    __ATOMIC_RELAXED, __HIP_MEMORY_SCOPE_AGENT);
          unsigned long long q1 = __hip_atomic_load(hrow + kk * 8 + lg * 2 + 1,
                                                    __ATOMIC_RELAXED, __HIP_MEMORY_SCOPE_AGENT);
          union { unsigned long long q[2]; bf16x8 v; } u;
          u.q[0] = q0; u.q[1] = q1; af = u.v;
        }
        const bf16x8* w0 = (const bf16x8*)(smem + LDS_WHH + (size_t)((kk * 2 + 0) * 64 + lane) * 16);
        const bf16x8* w1 = (const bf16x8*)(smem + LDS_WHH + (size_t)((kk * 2 + 1) * 64 + lane) * 16);
        acc0 = __builtin_amdgcn_mfma_f32_16x16x32_bf16(af, *w0, acc0, 0, 0, 0);
        acc1 = __builtin_amdgcn_mfma_f32_16x16x32_bf16(af, *w1, acc1, 0, 0, 0);
      }
    }

    // ---- epilogue: bias + relu (regs), bf16 into LDS transpose tile ----
    float p0v[4], p1v[4];
    if (lg < 2) {
      #pragma unroll
      for (int i = 0; i < 4; ++i) {
        const int r4 = lg * 4 + i;       // batch row 0..7
        const float p0 = fmaxf(acc0[i] + bs0, 0.f);
        const float p1 = fmaxf(acc1[i] + bs1, 0.f);
        p0v[i] = p0; p1v[i] = p1;
        *(unsigned short*)(smem + LDS_HT + r4 * 64 + c * 2)        = f2bf(p0);
        *(unsigned short*)(smem + LDS_HT + r4 * 64 + (16 + c) * 2) = f2bf(p1);
      }
    }
    __syncthreads();                     // order hT writes before reads (1 wave)

    // ---- flush hT: lane -> (row = lane>>3, 4 cols at (lane&7)*4), one u64 ----
    {
      unsigned long long q =
          *(const unsigned long long*)(smem + LDS_HT + (lane >> 3) * 64 + (lane & 7) * 8);
      unsigned long long* dst = hbuf + ((size_t)((t + 1) & 1) * 64 + b0 + (lane >> 3)) * 256
                                + (size_t)(jb / 4 + (lane & 7));
      __hip_atomic_store(dst, q, __ATOMIC_RELAXED, __HIP_MEMORY_SCOPE_AGENT);
    }
    // release: drain the sc1 h-stores to the coherence point, then signal.
    // (no buffer_wbl2 — the h-stores bypassed L2 already)
    asm volatile("s_waitcnt vmcnt(0)" ::: "memory");
    if (lane == 0)
      __hip_atomic_fetch_add(ctr + g * 64, 1u, __ATOMIC_RELAXED, __HIP_MEMORY_SCOPE_AGENT);

    // ---- out[] stores AFTER the signal (off the release critical path) ----
    if (lg < 2) {
      #pragma unroll
      for (int i = 0; i < 4; ++i) {
        const int r4 = lg * 4 + i;
        const size_t ob = ((size_t)(b0 + r4) * TT + t) * HH + jb + c;
        out[ob]      = p0v[i];
        out[ob + 16] = p1v[i];
      }
    }

    // ---- fill the sync bubble with x_proj for t+1 (no cross-wg dependency) ----
    if (t + 1 < TT) compute_xp(inp, smem, b0, t + 1, lane, x0, x1);
  }
}

extern "C" void kernel_launch(void* const* d_in, const int* in_sizes, int n_in,
                              void* d_out, int out_size, void* d_ws, size_t ws_size,
                              hipStream_t stream) {
  const float* inp = (const float*)d_in[0];
  const float* Wih = (const float*)d_in[1];
  const float* bih = (const float*)d_in[2];
  const float* Whh = (const float*)d_in[3];
  const float* bhh = (const float*)d_in[4];
  float* out = (float*)d_out;

  // ws: [0, 262144) hbuf (2 x 64 x 1024 bf16); [262144, +2048) counters (8 x 64 uints)
  unsigned long long* hbuf = (unsigned long long*)d_ws;
  unsigned int* ctr = (unsigned int*)((char*)d_ws + 262144);

  hipMemsetAsync(ctr, 0, 2048, stream);
  hipFuncSetAttribute((const void*)rnn_kernel,
                      hipFuncAttributeMaxDynamicSharedMemorySize, LDS_TOTAL);
  hipLaunchKernelGGL(rnn_kernel, dim3(256), dim3(64), LDS_TOTAL, stream,
                     inp, Wih, bih, Whh, bhh, out, hbuf, ctr);
}

// Round 7
// 34552.881 us; speedup vs baseline: 1.2362x; 1.0445x over previous
//
#include <hip/hip_runtime.h>

// NaiveRNN on MI355X: persistent kernel, 8 independent groups (one per XCD
// under blockIdx%8 round-robin), 32 wgs/group. Each wg: 32 output columns,
// W_hh/W_ih slices pre-packed as MFMA B-fragments in LDS. h broadcast through
// agent-scope ATOMICS only (no agent fences — r2: fences cost 3.6us/step).
// r5: group barrier = per-wg padded FLAG STORES + wave-parallel flag poll.
//   (r2's single counter: 32 same-address agent RMWs/step under a poll-load
//    storm serialized at the coherence point ~13us/step — Guideline 12.)
// Release ordering = s_waitcnt vmcnt(0) between h-stores and flag store.
// Acquire ordering = poll branch dependency + compiler barrier.

typedef __attribute__((ext_vector_type(8))) short bf16x8;   // 8 bf16 = 4 VGPRs
typedef __attribute__((ext_vector_type(4))) float f32x4;

#define TT 2048
#define II 512
#define HH 1024

// LDS layout (dynamic, 98816 B):
// [0,      65536): W_hh B-frags: slot ((kk*2+n2)*64 + lane)*16 B, kk<32
// [65536,  98304): W_ih B-frags: slot ((kk*2+n2)*64 + lane)*16 B, kk<16
// [98304,  98816): hT transpose buffer, 8 rows x 32 cols bf16
#define LDS_WHH 0
#define LDS_WIH 65536
#define LDS_HT  98304
#define LDS_TOTAL 98816

__device__ __forceinline__ unsigned short f2bf(float f) {
  union { __bf16 b; unsigned short s; } u;
  u.b = (__bf16)f;                       // RNE convert
  return u.s;
}

// x_proj fragments for time step tx: x[n2] = sum_k inputs[b][tx][k]*W_ih[j][k]
__device__ __forceinline__ void compute_xp(const float* __restrict__ inp,
                                           char* smem, int b0, int tx, int lane,
                                           f32x4& x0, f32x4& x1) {
  const int c = lane & 15, lg = lane >> 4;
  f32x4 z = {0.f, 0.f, 0.f, 0.f};
  x0 = z; x1 = z;
  const bool act = c < 8;                // batch rows 0..7 of the 16-row M tile
  const float* base = inp + ((size_t)(b0 + (act ? c : 0)) * TT + tx) * II + lg * 8;
  #pragma unroll 4
  for (int kk = 0; kk < 16; ++kk) {
    bf16x8 af = {0, 0, 0, 0, 0, 0, 0, 0};
    if (act) {
      f32x4 a = *(const f32x4*)(base + kk * 32);
      f32x4 b = *(const f32x4*)(base + kk * 32 + 4);
      #pragma unroll
      for (int i = 0; i < 4; ++i) {
        af[i]     = (short)f2bf(a[i]);
        af[4 + i] = (short)f2bf(b[i]);
      }
    }
    const bf16x8* w0 = (const bf16x8*)(smem + LDS_WIH + (size_t)((kk * 2 + 0) * 64 + lane) * 16);
    const bf16x8* w1 = (const bf16x8*)(smem + LDS_WIH + (size_t)((kk * 2 + 1) * 64 + lane) * 16);
    x0 = __builtin_amdgcn_mfma_f32_16x16x32_bf16(af, *w0, x0, 0, 0, 0);
    x1 = __builtin_amdgcn_mfma_f32_16x16x32_bf16(af, *w1, x1, 0, 0, 0);
  }
}

extern "C" __global__ void __launch_bounds__(64)
rnn_kernel(const float* __restrict__ inp,   // [64][2048][512]
           const float* __restrict__ Wih,   // [1024][512]
           const float* __restrict__ bih,   // [1024]
           const float* __restrict__ Whh,   // [1024][1024]
           const float* __restrict__ bhh,   // [1024]
           float* __restrict__ out,         // [64][2048][1024]
           unsigned long long* __restrict__ hbuf,  // [2][64][256] u64 (bf16 x4)
           unsigned int* __restrict__ flags)       // [8][32] slots, 16-dword stride
{
  extern __shared__ char smem[];
  const int lane = threadIdx.x;            // 0..63
  const int c  = lane & 15;
  const int lg = lane >> 4;
  const int wg = blockIdx.x;               // 0..255
  const int g  = wg & 7;                   // group (XCD under %8 round-robin)
  const int w  = wg >> 3;                  // 0..31 within group
  const int jb = w * 32;                   // output-column base
  const int b0 = g * 8;                    // batch base

  // ---- stage W_hh fragments: lane holds Whh[jb+n2*16+c][kk*32+lg*8 + 0..7] ----
  for (int kk = 0; kk < 32; ++kk)
    for (int n2 = 0; n2 < 2; ++n2) {
      const float* s = Whh + (size_t)(jb + n2 * 16 + c) * HH + kk * 32 + lg * 8;
      f32x4 a = *(const f32x4*)s;
      f32x4 b = *(const f32x4*)(s + 4);
      bf16x8 f;
      #pragma unroll
      for (int i = 0; i < 4; ++i) { f[i] = (short)f2bf(a[i]); f[4 + i] = (short)f2bf(b[i]); }
      *(bf16x8*)(smem + LDS_WHH + (size_t)((kk * 2 + n2) * 64 + lane) * 16) = f;
    }
  // ---- stage W_ih fragments ----
  for (int kk = 0; kk < 16; ++kk)
    for (int n2 = 0; n2 < 2; ++n2) {
      const float* s = Wih + (size_t)(jb + n2 * 16 + c) * II + kk * 32 + lg * 8;
      f32x4 a = *(const f32x4*)s;
      f32x4 b = *(const f32x4*)(s + 4);
      bf16x8 f;
      #pragma unroll
      for (int i = 0; i < 4; ++i) { f[i] = (short)f2bf(a[i]); f[4 + i] = (short)f2bf(b[i]); }
      *(bf16x8*)(smem + LDS_WIH + (size_t)((kk * 2 + n2) * 64 + lane) * 16) = f;
    }
  const float bs0 = bih[jb + c]      + bhh[jb + c];
  const float bs1 = bih[jb + 16 + c] + bhh[jb + 16 + c];
  __syncthreads();

  const bool act = c < 8;
  // each lane polls one flag slot of its group (lanes 32-63 duplicate 0-31)
  const unsigned int* pollp = flags + (size_t)(g * 32 + (lane & 31)) * 16;
  unsigned int* sigp = flags + (size_t)(g * 32 + w) * 16;

  f32x4 x0, x1;
  compute_xp(inp, smem, b0, 0, lane, x0, x1);

  for (int t = 0; t < TT; ++t) {
    f32x4 acc0 = x0, acc1 = x1;          // start from x_proj[t] (+h part below)

    if (t > 0) {
      // ---- group barrier: wait until every wg has signaled step t-1 done ----
      unsigned int v = __hip_atomic_load(pollp, __ATOMIC_RELAXED, __HIP_MEMORY_SCOPE_AGENT);
      while (!__all(v >= (unsigned)t)) {
        __builtin_amdgcn_s_sleep(1);
        v = __hip_atomic_load(pollp, __ATOMIC_RELAXED, __HIP_MEMORY_SCOPE_AGENT);
      }
      // acquire: HW order is free (loads below can't issue before the poll
      // branch resolves); just stop the compiler from hoisting.
      asm volatile("" ::: "memory");
      const unsigned long long* hrow =
          hbuf + ((size_t)(t & 1) * 64 + b0 + (act ? c : 0)) * 256;
      #pragma unroll 8
      for (int kk = 0; kk < 32; ++kk) {
        bf16x8 af = {0, 0, 0, 0, 0, 0, 0, 0};
        if (act) {
          unsigned long long q0 = __hip_atomic_load(hrow + kk * 8 + lg * 2,
                                                    __ATOMIC_RELAXED, __HIP_MEMORY_SCOPE_AGENT);
          unsigned long long q1 = __hip_atomic_load(hrow + kk * 8 + lg * 2 + 1,
                                                    __ATOMIC_RELAXED, __HIP_MEMORY_SCOPE_AGENT);
          union { unsigned long long q[2]; bf16x8 v; } u;
          u.q[0] = q0; u.q[1] = q1; af = u.v;
        }
        const bf16x8* w0 = (const bf16x8*)(smem + LDS_WHH + (size_t)((kk * 2 + 0) * 64 + lane) * 16);
        const bf16x8* w1 = (const bf16x8*)(smem + LDS_WHH + (size_t)((kk * 2 + 1) * 64 + lane) * 16);
        acc0 = __builtin_amdgcn_mfma_f32_16x16x32_bf16(af, *w0, acc0, 0, 0, 0);
        acc1 = __builtin_amdgcn_mfma_f32_16x16x32_bf16(af, *w1, acc1, 0, 0, 0);
      }
    }

    // ---- epilogue: bias + relu (regs), bf16 into LDS transpose tile ----
    float p0v[4], p1v[4];
    if (lg < 2) {
      #pragma unroll
      for (int i = 0; i < 4; ++i) {
        const int r4 = lg * 4 + i;       // batch row 0..7
        const float p0 = fmaxf(acc0[i] + bs0, 0.f);
        const float p1 = fmaxf(acc1[i] + bs1, 0.f);
        p0v[i] = p0; p1v[i] = p1;
        *(unsigned short*)(smem + LDS_HT + r4 * 64 + c * 2)        = f2bf(p0);
        *(unsigned short*)(smem + LDS_HT + r4 * 64 + (16 + c) * 2) = f2bf(p1);
      }
    }
    __syncthreads();                     // order hT writes before reads (1 wave)

    // ---- flush hT: lane -> (row = lane>>3, 4 cols at (lane&7)*4), one u64 ----
    {
      unsigned long long q =
          *(const unsigned long long*)(smem + LDS_HT + (lane >> 3) * 64 + (lane & 7) * 8);
      unsigned long long* dst = hbuf + ((size_t)((t + 1) & 1) * 64 + b0 + (lane >> 3)) * 256
                                + (size_t)(jb / 4 + (lane & 7));
      __hip_atomic_store(dst, q, __ATOMIC_RELAXED, __HIP_MEMORY_SCOPE_AGENT);
    }
    // release: drain the sc1 h-stores to the coherence point, then signal
    // with a plain store to this wg's OWN padded flag slot (no RMW).
    asm volatile("s_waitcnt vmcnt(0)" ::: "memory");
    if (lane == 0)
      __hip_atomic_store(sigp, (unsigned)(t + 1), __ATOMIC_RELAXED, __HIP_MEMORY_SCOPE_AGENT);

    // ---- out[] stores AFTER the signal (off the release critical path) ----
    if (lg < 2) {
      #pragma unroll
      for (int i = 0; i < 4; ++i) {
        const int r4 = lg * 4 + i;
        const size_t ob = ((size_t)(b0 + r4) * TT + t) * HH + jb + c;
        out[ob]      = p0v[i];
        out[ob + 16] = p1v[i];
      }
    }

    // ---- fill the sync bubble with x_proj for t+1 (no cross-wg dependency) ----
    if (t + 1 < TT) compute_xp(inp, smem, b0, t + 1, lane, x0, x1);
  }
}

extern "C" void kernel_launch(void* const* d_in, const int* in_sizes, int n_in,
                              void* d_out, int out_size, void* d_ws, size_t ws_size,
                              hipStream_t stream) {
  const float* inp = (const float*)d_in[0];
  const float* Wih = (const float*)d_in[1];
  const float* bih = (const float*)d_in[2];
  const float* Whh = (const float*)d_in[3];
  const float* bhh = (const float*)d_in[4];
  float* out = (float*)d_out;

  // ws: [0, 262144) hbuf (2 x 64 x 1024 bf16);
  //     [262144, 278528) flags: 8 groups x 32 wgs x 64B-stride slots
  unsigned long long* hbuf = (unsigned long long*)d_ws;
  unsigned int* flags = (unsigned int*)((char*)d_ws + 262144);

  hipMemsetAsync(flags, 0, 16384, stream);
  hipFuncSetAttribute((const void*)rnn_kernel,
                      hipFuncAttributeMaxDynamicSharedMemorySize, LDS_TOTAL);
  hipLaunchKernelGGL(rnn_kernel, dim3(256), dim3(64), LDS_TOTAL, stream,
                     inp, Wih, bih, Whh, bhh, out, hbuf, flags);
}